// Round 1
// baseline (1557.287 us; speedup 1.0000x reference)
//
#include <hip/hip_runtime.h>

#define N_NODES 100000
#define N_EDGES 1600000
#define D 128
#define NLAYERS 4
#define NGRAPH 100
#define NOUT 10
#define BN_EPS 1e-5f

// ---------------------------------------------------------------- degrees
__global__ void deg_kernel(const int* __restrict__ src, const int* __restrict__ dst,
                           int* __restrict__ deg_out, int* __restrict__ deg_in) {
    int e = blockIdx.x * blockDim.x + threadIdx.x;
    if (e < N_EDGES) {
        atomicAdd(&deg_out[src[e]], 1);
        atomicAdd(&deg_in[dst[e]], 1);
    }
}

__global__ void norm_kernel(const int* __restrict__ deg_out, const int* __restrict__ deg_in,
                            float* __restrict__ norm_src, float* __restrict__ norm_dst) {
    int v = blockIdx.x * blockDim.x + threadIdx.x;
    if (v < N_NODES) {
        norm_src[v] = rsqrtf((float)max(deg_out[v], 1));
        norm_dst[v] = rsqrtf((float)max(deg_in[v], 1));
    }
}

// ---------------------------------------------------------------- scan (row_ptr)
__global__ void scan1_kernel(const int* __restrict__ deg, int* __restrict__ rp,
                             int* __restrict__ blksum) {
    __shared__ int s[256];
    int t = threadIdx.x;
    int base = blockIdx.x * 1024 + t * 4;
    int v0 = 0, v1 = 0, v2 = 0, v3 = 0;
    if (base + 0 < N_NODES) v0 = deg[base + 0];
    if (base + 1 < N_NODES) v1 = deg[base + 1];
    if (base + 2 < N_NODES) v2 = deg[base + 2];
    if (base + 3 < N_NODES) v3 = deg[base + 3];
    int sum = v0 + v1 + v2 + v3;
    s[t] = sum;
    __syncthreads();
    for (int off = 1; off < 256; off <<= 1) {
        int x = 0;
        if (t >= off) x = s[t - off];
        __syncthreads();
        s[t] += x;
        __syncthreads();
    }
    int run = s[t] - sum;   // exclusive offset of this thread within block
    if (base + 0 < N_NODES) rp[base + 0] = run; run += v0;
    if (base + 1 < N_NODES) rp[base + 1] = run; run += v1;
    if (base + 2 < N_NODES) rp[base + 2] = run; run += v2;
    if (base + 3 < N_NODES) rp[base + 3] = run;
    if (t == 255) blksum[blockIdx.x] = s[255];
}

__global__ void scan2_kernel(int* __restrict__ blksum, int nb, int* __restrict__ rp) {
    __shared__ int s[128];
    int t = threadIdx.x;
    int v = (t < nb) ? blksum[t] : 0;
    s[t] = v;
    __syncthreads();
    for (int off = 1; off < 128; off <<= 1) {
        int x = 0;
        if (t >= off) x = s[t - off];
        __syncthreads();
        s[t] += x;
        __syncthreads();
    }
    if (t < nb) blksum[t] = s[t] - v;      // exclusive block offsets
    if (t == 127) rp[N_NODES] = s[127];    // grand total (== E)
}

__global__ void scan3_kernel(int* __restrict__ rp, const int* __restrict__ blksum) {
    int i = blockIdx.x * blockDim.x + threadIdx.x;
    if (i < N_NODES) rp[i] += blksum[i >> 10];
}

__global__ void scatter_kernel(const int* __restrict__ src, const int* __restrict__ dst,
                               const int* __restrict__ rp, int* __restrict__ cursor,
                               int* __restrict__ col_idx) {
    int e = blockIdx.x * blockDim.x + threadIdx.x;
    if (e < N_EDGES) {
        int d = dst[e];
        int pos = atomicAdd(&cursor[d], 1);
        col_idx[rp[d] + pos] = src[e];
    }
}

// ---------------------------------------------------------------- aggregation
// thread -> (node v = tid/32, 4 columns). half-wave reads one 512B row chunk.
__global__ void agg_kernel(const float* __restrict__ h, const int* __restrict__ rp,
                           const int* __restrict__ col_idx, const float* __restrict__ norm_src,
                           const float* __restrict__ norm_dst, float* __restrict__ agg) {
    int tid = blockIdx.x * blockDim.x + threadIdx.x;
    int v = tid >> 5;
    if (v >= N_NODES) return;
    int c4 = (tid & 31) << 2;
    int e0 = rp[v], e1 = rp[v + 1];
    float ax = 0.f, ay = 0.f, az = 0.f, aw = 0.f;
    for (int e = e0; e < e1; ++e) {
        int u = col_idx[e];
        float ns = norm_src[u];
        const float4 hv = *reinterpret_cast<const float4*>(h + (size_t)u * D + c4);
        ax = fmaf(hv.x, ns, ax);
        ay = fmaf(hv.y, ns, ay);
        az = fmaf(hv.z, ns, az);
        aw = fmaf(hv.w, ns, aw);
    }
    float nd = norm_dst[v];
    float4 o = {ax * nd, ay * nd, az * nd, aw * nd};
    *reinterpret_cast<float4*>(agg + (size_t)v * D + c4) = o;
}

// ---------------------------------------------------------------- GEMM (in-place) + BN stats
// block: 256 threads, 64 rows x 128 cols; thread: 8 rows x 4 cols register tile.
__global__ __launch_bounds__(256) void gemm_stats_kernel(float* __restrict__ inout,
        const float* __restrict__ Wl, const float* __restrict__ bl,
        float* __restrict__ stats, int nrows) {
    __shared__ float sIn[32][68];   // [k][row], padded
    __shared__ float sW[32][128];   // [k][col]
    int t = threadIdx.x;
    int tx = t & 31;                // col group: cols 4*tx .. 4*tx+3
    int ty = t >> 5;                // row group: rows 8*ty .. 8*ty+7
    int rowbase = blockIdx.x * 64;

    float acc[8][4];
#pragma unroll
    for (int r = 0; r < 8; ++r)
#pragma unroll
        for (int c = 0; c < 4; ++c) acc[r][c] = 0.f;

    for (int kt = 0; kt < D; kt += 32) {
        // stage input tile transposed: sIn[k][r] = in[rowbase+r][kt+k]
#pragma unroll
        for (int i = 0; i < 2; ++i) {
            int cch = t + i * 256;          // 0..511 float4 chunks
            int r = cch >> 3;               // 0..63
            int kk = (cch & 7) << 2;        // 0..28
            int row = rowbase + r;
            float4 v = {0.f, 0.f, 0.f, 0.f};
            if (row < nrows)
                v = *reinterpret_cast<const float4*>(inout + (size_t)row * D + kt + kk);
            sIn[kk + 0][r] = v.x;
            sIn[kk + 1][r] = v.y;
            sIn[kk + 2][r] = v.z;
            sIn[kk + 3][r] = v.w;
        }
        // stage W tile: sW[k][c] = W[kt+k][c]
#pragma unroll
        for (int i = 0; i < 4; ++i) {
            int cch = t + i * 256;          // 0..1023 float4 chunks
            int k = cch >> 5;
            int cc = (cch & 31) << 2;
            *reinterpret_cast<float4*>(&sW[k][cc]) =
                *reinterpret_cast<const float4*>(Wl + (size_t)(kt + k) * D + cc);
        }
        __syncthreads();
#pragma unroll
        for (int k = 0; k < 32; ++k) {
            float4 wv = *reinterpret_cast<float4*>(&sW[k][tx << 2]);
            float4 a0 = *reinterpret_cast<float4*>(&sIn[k][ty << 3]);
            float4 a1 = *reinterpret_cast<float4*>(&sIn[k][(ty << 3) + 4]);
            float av[8] = {a0.x, a0.y, a0.z, a0.w, a1.x, a1.y, a1.z, a1.w};
            float wc[4] = {wv.x, wv.y, wv.z, wv.w};
#pragma unroll
            for (int r = 0; r < 8; ++r)
#pragma unroll
                for (int c = 0; c < 4; ++c) acc[r][c] = fmaf(av[r], wc[c], acc[r][c]);
        }
        __syncthreads();
    }

    // epilogue: bias, in-place store, column partial sums
    float4 bias = *reinterpret_cast<const float4*>(bl + (tx << 2));
    float bs[4] = {bias.x, bias.y, bias.z, bias.w};
    float s[4] = {0.f, 0.f, 0.f, 0.f};
    float sq[4] = {0.f, 0.f, 0.f, 0.f};
#pragma unroll
    for (int r = 0; r < 8; ++r) {
        int row = rowbase + (ty << 3) + r;
        if (row < nrows) {
            float o[4];
#pragma unroll
            for (int c = 0; c < 4; ++c) {
                o[c] = acc[r][c] + bs[c];
                s[c] += o[c];
                sq[c] += o[c] * o[c];
            }
            float4 ov = {o[0], o[1], o[2], o[3]};
            *reinterpret_cast<float4*>(inout + (size_t)row * D + (tx << 2)) = ov;
        }
    }
    // reduce across ty groups in LDS, then 1 atomic per column per block
    float* red = &sIn[0][0];   // reuse (needs 4KB)
#pragma unroll
    for (int c = 0; c < 4; ++c) red[t * 4 + c] = s[c];
    __syncthreads();
    if (ty == 0) {
#pragma unroll
        for (int c = 0; c < 4; ++c) {
            float tot = 0.f;
            for (int yy = 0; yy < 8; ++yy) tot += red[(yy * 32 + tx) * 4 + c];
            atomicAdd(&stats[(tx << 2) + c], tot);
        }
    }
    __syncthreads();
#pragma unroll
    for (int c = 0; c < 4; ++c) red[t * 4 + c] = sq[c];
    __syncthreads();
    if (ty == 0) {
#pragma unroll
        for (int c = 0; c < 4; ++c) {
            float tot = 0.f;
            for (int yy = 0; yy < 8; ++yy) tot += red[(yy * 32 + tx) * 4 + c];
            atomicAdd(&stats[D + (tx << 2) + c], tot);
        }
    }
}

// ---------------------------------------------------------------- BN finalize + apply
__global__ void bn_finalize_kernel(float* __restrict__ stats, const float* __restrict__ gamma,
                                   const float* __restrict__ beta) {
    int c = threadIdx.x;   // 128
    float mu = stats[c] * (1.f / N_NODES);
    float var = stats[D + c] * (1.f / N_NODES) - mu * mu;
    float sc = rsqrtf(var + BN_EPS) * gamma[c];
    stats[2 * D + c] = sc;
    stats[3 * D + c] = beta[c] - mu * sc;
}

__global__ void bn_apply_kernel(float* __restrict__ h, const float* __restrict__ x,
                                const float* __restrict__ stats, int residual) {
    int tid = blockIdx.x * blockDim.x + threadIdx.x;
    int v = tid >> 5;
    if (v >= N_NODES) return;
    int c4 = (tid & 31) << 2;
    float4 hv = *reinterpret_cast<float4*>(h + (size_t)v * D + c4);
    float4 sc = *reinterpret_cast<const float4*>(stats + 2 * D + c4);
    float4 sh = *reinterpret_cast<const float4*>(stats + 3 * D + c4);
    float o[4];
    o[0] = fmaf(hv.x, sc.x, sh.x);
    o[1] = fmaf(hv.y, sc.y, sh.y);
    o[2] = fmaf(hv.z, sc.z, sh.z);
    o[3] = fmaf(hv.w, sc.w, sh.w);
#pragma unroll
    for (int c = 0; c < 4; ++c) o[c] = fmaxf(o[c], 0.f);
    if (residual) {
        float4 xv = *reinterpret_cast<const float4*>(x + (size_t)v * D + c4);
        o[0] += xv.x; o[1] += xv.y; o[2] += xv.z; o[3] += xv.w;
    }
    float4 ov = {o[0], o[1], o[2], o[3]};
    *reinterpret_cast<float4*>(h + (size_t)v * D + c4) = ov;
}

// ---------------------------------------------------------------- pooling + head
// node_graph_id is sorted: run-length accumulate, few atomics.
__global__ void pool_kernel(const float* __restrict__ h, const int* __restrict__ gid,
                            float* __restrict__ pooled) {
    int base = blockIdx.x * 128;
    int c4 = (threadIdx.x & 31) << 2;
    int sub = threadIdx.x >> 5;            // 0..7, 16 rows each
    int r0 = base + sub * 16;
    if (r0 >= N_NODES) return;
    int r1 = min(r0 + 16, N_NODES);
    int gcur = gid[r0];
    float ax = 0.f, ay = 0.f, az = 0.f, aw = 0.f;
    for (int row = r0; row < r1; ++row) {
        int g = gid[row];
        const float4 hv = *reinterpret_cast<const float4*>(h + (size_t)row * D + c4);
        if (g != gcur) {
            atomicAdd(&pooled[gcur * D + c4 + 0], ax);
            atomicAdd(&pooled[gcur * D + c4 + 1], ay);
            atomicAdd(&pooled[gcur * D + c4 + 2], az);
            atomicAdd(&pooled[gcur * D + c4 + 3], aw);
            ax = ay = az = aw = 0.f;
            gcur = g;
        }
        ax += hv.x; ay += hv.y; az += hv.z; aw += hv.w;
    }
    atomicAdd(&pooled[gcur * D + c4 + 0], ax);
    atomicAdd(&pooled[gcur * D + c4 + 1], ay);
    atomicAdd(&pooled[gcur * D + c4 + 2], az);
    atomicAdd(&pooled[gcur * D + c4 + 3], aw);
}

__global__ void head_kernel(const float* __restrict__ pooled, const float* __restrict__ Wp,
                            const float* __restrict__ bp, float* __restrict__ out) {
    int tid = blockIdx.x * blockDim.x + threadIdx.x;
    if (tid >= NGRAPH * NOUT) return;
    int g = tid / NOUT, o = tid % NOUT;
    float sum = bp[o];
    for (int k = 0; k < D; ++k) sum = fmaf(pooled[g * D + k], Wp[k * NOUT + o], sum);
    out[tid] = sum;
}

// ----------------------------------------------------------------
extern "C" void kernel_launch(void* const* d_in, const int* in_sizes, int n_in,
                              void* d_out, int out_size, void* d_ws, size_t ws_size,
                              hipStream_t stream) {
    const float* h     = (const float*)d_in[0];
    const float* W     = (const float*)d_in[1];
    const float* b     = (const float*)d_in[2];
    const float* gamma = (const float*)d_in[3];
    const float* beta  = (const float*)d_in[4];
    const float* Wp    = (const float*)d_in[5];
    const float* bp    = (const float*)d_in[6];
    const int*   src   = (const int*)d_in[7];
    const int*   dst   = (const int*)d_in[8];
    const int*   gid   = (const int*)d_in[9];
    float* out = (float*)d_out;

    char* ws = (char*)d_ws;
    size_t off = 0;
    auto alloc = [&](size_t bytes) { char* p = ws + off; off = (off + bytes + 511) & ~(size_t)511; return p; };
    float* bufA     = (float*)alloc((size_t)N_NODES * D * 4);
    float* bufB     = (float*)alloc((size_t)N_NODES * D * 4);
    int*   degO     = (int*)alloc((size_t)N_NODES * 4);
    int*   degI     = (int*)alloc((size_t)N_NODES * 4);
    int*   row_ptr  = (int*)alloc((size_t)(N_NODES + 1) * 4);
    int*   cursor   = (int*)alloc((size_t)N_NODES * 4);
    int*   col_idx  = (int*)alloc((size_t)N_EDGES * 4);
    float* norm_src = (float*)alloc((size_t)N_NODES * 4);
    float* norm_dst = (float*)alloc((size_t)N_NODES * 4);
    float* stats    = (float*)alloc(4 * D * 4);
    float* pooled   = (float*)alloc((size_t)NGRAPH * D * 4);
    int*   blksum   = (int*)alloc(128 * 4);

    // ---- CSR build (per call; src/dst are inputs)
    hipMemsetAsync(degO, 0, (size_t)N_NODES * 4, stream);
    hipMemsetAsync(degI, 0, (size_t)N_NODES * 4, stream);
    hipMemsetAsync(cursor, 0, (size_t)N_NODES * 4, stream);
    deg_kernel<<<(N_EDGES + 255) / 256, 256, 0, stream>>>(src, dst, degO, degI);
    norm_kernel<<<(N_NODES + 255) / 256, 256, 0, stream>>>(degO, degI, norm_src, norm_dst);
    int nb = (N_NODES + 1023) / 1024;  // 98
    scan1_kernel<<<nb, 256, 0, stream>>>(degI, row_ptr, blksum);
    scan2_kernel<<<1, 128, 0, stream>>>(blksum, nb, row_ptr);
    scan3_kernel<<<(N_NODES + 255) / 256, 256, 0, stream>>>(row_ptr, blksum);
    scatter_kernel<<<(N_EDGES + 255) / 256, 256, 0, stream>>>(src, dst, row_ptr, cursor, col_idx);

    // ---- layers
    const float* x = h;
    float* cur = bufA;
    for (int l = 0; l < NLAYERS; ++l) {
        agg_kernel<<<(N_NODES * 32 + 255) / 256, 256, 0, stream>>>(x, row_ptr, col_idx,
                                                                   norm_src, norm_dst, cur);
        hipMemsetAsync(stats, 0, 4 * D * 4, stream);
        gemm_stats_kernel<<<(N_NODES + 63) / 64, 256, 0, stream>>>(cur, W + (size_t)l * D * D,
                                                                   b + (size_t)l * D, stats, N_NODES);
        bn_finalize_kernel<<<1, 128, 0, stream>>>(stats, gamma + (size_t)l * D, beta + (size_t)l * D);
        bn_apply_kernel<<<(N_NODES * 32 + 255) / 256, 256, 0, stream>>>(cur, x, stats, l > 0 ? 1 : 0);
        x = cur;
        cur = (cur == bufA) ? bufB : bufA;
    }

    // ---- pooling + head
    hipMemsetAsync(pooled, 0, (size_t)NGRAPH * D * 4, stream);
    pool_kernel<<<(N_NODES + 127) / 128, 256, 0, stream>>>(x, gid, pooled);
    head_kernel<<<4, 256, 0, stream>>>(pooled, Wp, bp, out);
}

// Round 2
// 850.665 us; speedup vs baseline: 1.8307x; 1.8307x over previous
//
#include <hip/hip_runtime.h>

#define N_NODES 100000
#define N_EDGES 1600000
#define D 128
#define NLAYERS 4
#define NGRAPH 100
#define NOUT 10
#define BN_EPS 1e-5f

typedef __attribute__((ext_vector_type(8))) short bf16x8;
typedef __attribute__((ext_vector_type(8))) unsigned short u16x8;
typedef __attribute__((ext_vector_type(4))) float f32x4;

static __device__ __forceinline__ unsigned short f2bf(float f) {
    unsigned u = __builtin_bit_cast(unsigned, f);
    unsigned r = (u + 0x7fffu + ((u >> 16) & 1u)) >> 16;
    return (unsigned short)r;
}
static __device__ __forceinline__ float bf2f(unsigned short b) {
    unsigned u = ((unsigned)b) << 16;
    return __builtin_bit_cast(float, u);
}

// ---------------------------------------------------------------- degrees
__global__ void deg_kernel(const int* __restrict__ src, const int* __restrict__ dst,
                           int* __restrict__ deg_out, int* __restrict__ deg_in) {
    int e = blockIdx.x * blockDim.x + threadIdx.x;
    if (e < N_EDGES) {
        atomicAdd(&deg_out[src[e]], 1);
        atomicAdd(&deg_in[dst[e]], 1);
    }
}

__global__ void norm_kernel(const int* __restrict__ deg_out, const int* __restrict__ deg_in,
                            float* __restrict__ norm_src, float* __restrict__ norm_dst) {
    int v = blockIdx.x * blockDim.x + threadIdx.x;
    if (v < N_NODES) {
        norm_src[v] = rsqrtf((float)max(deg_out[v], 1));
        norm_dst[v] = rsqrtf((float)max(deg_in[v], 1));
    }
}

// ---------------------------------------------------------------- scan (row_ptr)
__global__ void scan1_kernel(const int* __restrict__ deg, int* __restrict__ rp,
                             int* __restrict__ blksum) {
    __shared__ int s[256];
    int t = threadIdx.x;
    int base = blockIdx.x * 1024 + t * 4;
    int v0 = 0, v1 = 0, v2 = 0, v3 = 0;
    if (base + 0 < N_NODES) v0 = deg[base + 0];
    if (base + 1 < N_NODES) v1 = deg[base + 1];
    if (base + 2 < N_NODES) v2 = deg[base + 2];
    if (base + 3 < N_NODES) v3 = deg[base + 3];
    int sum = v0 + v1 + v2 + v3;
    s[t] = sum;
    __syncthreads();
    for (int off = 1; off < 256; off <<= 1) {
        int x = 0;
        if (t >= off) x = s[t - off];
        __syncthreads();
        s[t] += x;
        __syncthreads();
    }
    int run = s[t] - sum;
    if (base + 0 < N_NODES) rp[base + 0] = run; run += v0;
    if (base + 1 < N_NODES) rp[base + 1] = run; run += v1;
    if (base + 2 < N_NODES) rp[base + 2] = run; run += v2;
    if (base + 3 < N_NODES) rp[base + 3] = run;
    if (t == 255) blksum[blockIdx.x] = s[255];
}

__global__ void scan2_kernel(int* __restrict__ blksum, int nb, int* __restrict__ rp) {
    __shared__ int s[128];
    int t = threadIdx.x;
    int v = (t < nb) ? blksum[t] : 0;
    s[t] = v;
    __syncthreads();
    for (int off = 1; off < 128; off <<= 1) {
        int x = 0;
        if (t >= off) x = s[t - off];
        __syncthreads();
        s[t] += x;
        __syncthreads();
    }
    if (t < nb) blksum[t] = s[t] - v;
    if (t == 127) rp[N_NODES] = s[127];
}

__global__ void scan3_kernel(int* __restrict__ rp, const int* __restrict__ blksum) {
    int i = blockIdx.x * blockDim.x + threadIdx.x;
    if (i < N_NODES) rp[i] += blksum[i >> 10];
}

__global__ void scatter_kernel(const int* __restrict__ src, const int* __restrict__ dst,
                               const int* __restrict__ rp, int* __restrict__ cursor,
                               int* __restrict__ col_idx) {
    int e = blockIdx.x * blockDim.x + threadIdx.x;
    if (e < N_EDGES) {
        int d = dst[e];
        int pos = atomicAdd(&cursor[d], 1);
        col_idx[rp[d] + pos] = src[e];
    }
}

// ---------------------------------------------------------------- weight prep
// Wt_swz[l]: bf16, B^T layout [col][k], bytes XOR-swizzled so that the GEMM's
// ds_read_b128 B-fragment reads are bank-conflict-free after a LINEAR LDS copy.
__global__ void wprep_kernel(const float* __restrict__ W, unsigned short* __restrict__ Wt) {
    int i = blockIdx.x * blockDim.x + threadIdx.x;
    if (i >= NLAYERS * D * D) return;
    int l = i >> 14;
    int r = i & (D * D - 1);
    int col = r >> 7;
    int k = r & 127;
    float v = W[(size_t)l * D * D + k * D + col];
    int byteoff = col * 256 + k * 2;
    int swz = byteoff ^ ((col & 7) << 4);
    Wt[(size_t)l * D * D + (swz >> 1)] = f2bf(v);
}

// ---------------------------------------------------------------- prep hs (layer 0 input)
// hs = bf16(h * norm_src)
__global__ void prep_hs_kernel(const float* __restrict__ h, const float* __restrict__ norm_src,
                               unsigned short* __restrict__ hs) {
    int tid = blockIdx.x * blockDim.x + threadIdx.x;
    int v = tid >> 5;
    if (v >= N_NODES) return;
    int c4 = (tid & 31) << 2;
    float ns = norm_src[v];
    float4 hv = *reinterpret_cast<const float4*>(h + (size_t)v * D + c4);
    unsigned short o[4] = {f2bf(hv.x * ns), f2bf(hv.y * ns), f2bf(hv.z * ns), f2bf(hv.w * ns)};
    *reinterpret_cast<ushort4*>(hs + (size_t)v * D + c4) = *reinterpret_cast<ushort4*>(o);
}

// ---------------------------------------------------------------- aggregation (bf16 in/out)
// 16 threads per node, 8 cols each (16B gathers). norm_src pre-applied in hs.
__global__ void agg_kernel(const unsigned short* __restrict__ hs, const int* __restrict__ rp,
                           const int* __restrict__ col_idx, const float* __restrict__ norm_dst,
                           unsigned short* __restrict__ aggb) {
    int tid = blockIdx.x * blockDim.x + threadIdx.x;
    int v = tid >> 4;
    if (v >= N_NODES) return;
    int c8 = (tid & 15) << 3;
    int e0 = rp[v], e1 = rp[v + 1];
    float acc[8] = {0.f, 0.f, 0.f, 0.f, 0.f, 0.f, 0.f, 0.f};
    for (int e = e0; e < e1; ++e) {
        int u = col_idx[e];
        u16x8 hv = *reinterpret_cast<const u16x8*>(hs + (size_t)u * D + c8);
#pragma unroll
        for (int j = 0; j < 8; ++j) acc[j] += bf2f(hv[j]);
    }
    float nd = norm_dst[v];
    unsigned short o[8];
#pragma unroll
    for (int j = 0; j < 8; ++j) o[j] = f2bf(acc[j] * nd);
    *reinterpret_cast<u16x8*>(aggb + (size_t)v * D + c8) = *reinterpret_cast<u16x8*>(o);
}

// ---------------------------------------------------------------- MFMA GEMM + BN stats
// block: 256 thr = 4 waves; wave owns 32 rows (2 row-frags) x 128 cols (8 col-frags).
// A: bf16 [M][128] from global. B: Wt_swz staged linearly into LDS (pre-swizzled).
__global__ __launch_bounds__(256) void gemm_mfma_kernel(const unsigned short* __restrict__ A,
        const unsigned short* __restrict__ Wt, const float* __restrict__ bl,
        float* __restrict__ outF, float* __restrict__ stats, int nrows) {
    __shared__ __align__(16) unsigned short sW[D * D];   // 32 KB
    int t = threadIdx.x;
    // linear stage: 32KB / 16B = 2048 chunks
#pragma unroll
    for (int i = 0; i < 8; ++i) {
        int idx = t + i * 256;
        reinterpret_cast<uint4*>(sW)[idx] = reinterpret_cast<const uint4*>(Wt)[idx];
    }
    __syncthreads();

    int wave = t >> 6;
    int lane = t & 63;
    int l15 = lane & 15;
    int lg = lane >> 4;       // 0..3
    int rowbase = blockIdx.x * 128 + wave * 32;

    f32x4 acc[2][8];
#pragma unroll
    for (int rf = 0; rf < 2; ++rf)
#pragma unroll
        for (int cf = 0; cf < 8; ++cf) acc[rf][cf] = (f32x4){0.f, 0.f, 0.f, 0.f};

#pragma unroll
    for (int ks = 0; ks < 4; ++ks) {
        bf16x8 a[2];
#pragma unroll
        for (int rf = 0; rf < 2; ++rf) {
            int r = rowbase + rf * 16 + l15;
            if (r >= nrows) r = nrows - 1;     // clamp; garbage rows masked on store
            a[rf] = *reinterpret_cast<const bf16x8*>(A + (size_t)r * D + ks * 32 + lg * 8);
        }
#pragma unroll
        for (int cf = 0; cf < 8; ++cf) {
            int col = cf * 16 + l15;
            int byteoff = (col * 256 + ks * 64 + lg * 16) ^ ((col & 7) << 4);
            bf16x8 bfrag = *reinterpret_cast<const bf16x8*>(
                reinterpret_cast<const char*>(sW) + byteoff);
            acc[0][cf] = __builtin_amdgcn_mfma_f32_16x16x32_bf16(a[0], bfrag, acc[0][cf], 0, 0, 0);
            acc[1][cf] = __builtin_amdgcn_mfma_f32_16x16x32_bf16(a[1], bfrag, acc[1][cf], 0, 0, 0);
        }
    }

    // epilogue: bias + store fp32 + fused BN partial stats (8-sliced atomics)
    int slice = (blockIdx.x & 7) * 2 * D;
#pragma unroll
    for (int cf = 0; cf < 8; ++cf) {
        int c = cf * 16 + l15;
        float bias = bl[c];
        float s = 0.f, sq = 0.f;
#pragma unroll
        for (int rf = 0; rf < 2; ++rf) {
            int rb = rowbase + rf * 16 + lg * 4;
#pragma unroll
            for (int j = 0; j < 4; ++j) {
                int row = rb + j;
                if (row < nrows) {
                    float val = acc[rf][cf][j] + bias;
                    outF[(size_t)row * D + c] = val;
                    s += val;
                    sq += val * val;
                }
            }
        }
        s += __shfl_xor(s, 16);
        s += __shfl_xor(s, 32);
        sq += __shfl_xor(sq, 16);
        sq += __shfl_xor(sq, 32);
        if (lg == 0) {
            atomicAdd(&stats[slice + c], s);
            atomicAdd(&stats[slice + D + c], sq);
        }
    }
}

// ---------------------------------------------------------------- BN finalize
__global__ void bn_finalize_kernel(const float* __restrict__ stats, const float* __restrict__ gamma,
                                   const float* __restrict__ beta, float* __restrict__ fin) {
    int c = threadIdx.x;   // 128
    float s = 0.f, sq = 0.f;
#pragma unroll
    for (int i = 0; i < 8; ++i) {
        s += stats[i * 2 * D + c];
        sq += stats[i * 2 * D + D + c];
    }
    float mu = s * (1.f / N_NODES);
    float var = sq * (1.f / N_NODES) - mu * mu;
    float sc = rsqrtf(var + BN_EPS) * gamma[c];
    fin[c] = sc;
    fin[D + c] = beta[c] - mu * sc;
}

// ---------------------------------------------------------------- BN apply (+relu,+residual) in-place
// also writes hs (bf16, * norm_src) for the next layer's aggregation
__global__ void bn_apply_kernel(float* __restrict__ g, const float* __restrict__ xres,
                                const float* __restrict__ fin, const float* __restrict__ norm_src,
                                unsigned short* __restrict__ hs, int residual, int write_hs) {
    int tid = blockIdx.x * blockDim.x + threadIdx.x;
    int v = tid >> 5;
    if (v >= N_NODES) return;
    int c4 = (tid & 31) << 2;
    float4 hv = *reinterpret_cast<float4*>(g + (size_t)v * D + c4);
    float4 sc = *reinterpret_cast<const float4*>(fin + c4);
    float4 sh = *reinterpret_cast<const float4*>(fin + D + c4);
    float o[4];
    o[0] = fmaxf(fmaf(hv.x, sc.x, sh.x), 0.f);
    o[1] = fmaxf(fmaf(hv.y, sc.y, sh.y), 0.f);
    o[2] = fmaxf(fmaf(hv.z, sc.z, sh.z), 0.f);
    o[3] = fmaxf(fmaf(hv.w, sc.w, sh.w), 0.f);
    if (residual) {
        float4 xv = *reinterpret_cast<const float4*>(xres + (size_t)v * D + c4);
        o[0] += xv.x; o[1] += xv.y; o[2] += xv.z; o[3] += xv.w;
    }
    float4 ov = {o[0], o[1], o[2], o[3]};
    *reinterpret_cast<float4*>(g + (size_t)v * D + c4) = ov;
    if (write_hs) {
        float ns = norm_src[v];
        unsigned short ob[4] = {f2bf(o[0] * ns), f2bf(o[1] * ns), f2bf(o[2] * ns), f2bf(o[3] * ns)};
        *reinterpret_cast<ushort4*>(hs + (size_t)v * D + c4) = *reinterpret_cast<ushort4*>(ob);
    }
}

// ---------------------------------------------------------------- pooling + head
__global__ void pool_kernel(const float* __restrict__ h, const int* __restrict__ gid,
                            float* __restrict__ pooled) {
    int base = blockIdx.x * 128;
    int c4 = (threadIdx.x & 31) << 2;
    int sub = threadIdx.x >> 5;
    int r0 = base + sub * 16;
    if (r0 >= N_NODES) return;
    int r1 = min(r0 + 16, N_NODES);
    int gcur = gid[r0];
    float ax = 0.f, ay = 0.f, az = 0.f, aw = 0.f;
    for (int row = r0; row < r1; ++row) {
        int g = gid[row];
        const float4 hv = *reinterpret_cast<const float4*>(h + (size_t)row * D + c4);
        if (g != gcur) {
            atomicAdd(&pooled[gcur * D + c4 + 0], ax);
            atomicAdd(&pooled[gcur * D + c4 + 1], ay);
            atomicAdd(&pooled[gcur * D + c4 + 2], az);
            atomicAdd(&pooled[gcur * D + c4 + 3], aw);
            ax = ay = az = aw = 0.f;
            gcur = g;
        }
        ax += hv.x; ay += hv.y; az += hv.z; aw += hv.w;
    }
    atomicAdd(&pooled[gcur * D + c4 + 0], ax);
    atomicAdd(&pooled[gcur * D + c4 + 1], ay);
    atomicAdd(&pooled[gcur * D + c4 + 2], az);
    atomicAdd(&pooled[gcur * D + c4 + 3], aw);
}

__global__ void head_kernel(const float* __restrict__ pooled, const float* __restrict__ Wp,
                            const float* __restrict__ bp, float* __restrict__ out) {
    int tid = blockIdx.x * blockDim.x + threadIdx.x;
    if (tid >= NGRAPH * NOUT) return;
    int g = tid / NOUT, o = tid % NOUT;
    float sum = bp[o];
    for (int k = 0; k < D; ++k) sum = fmaf(pooled[g * D + k], Wp[k * NOUT + o], sum);
    out[tid] = sum;
}

// ----------------------------------------------------------------
extern "C" void kernel_launch(void* const* d_in, const int* in_sizes, int n_in,
                              void* d_out, int out_size, void* d_ws, size_t ws_size,
                              hipStream_t stream) {
    const float* h     = (const float*)d_in[0];
    const float* W     = (const float*)d_in[1];
    const float* b     = (const float*)d_in[2];
    const float* gamma = (const float*)d_in[3];
    const float* beta  = (const float*)d_in[4];
    const float* Wp    = (const float*)d_in[5];
    const float* bp    = (const float*)d_in[6];
    const int*   src   = (const int*)d_in[7];
    const int*   dst   = (const int*)d_in[8];
    const int*   gid   = (const int*)d_in[9];
    float* out = (float*)d_out;

    char* ws = (char*)d_ws;
    size_t off = 0;
    auto alloc = [&](size_t bytes) { char* p = ws + off; off = (off + bytes + 511) & ~(size_t)511; return p; };
    float* F0       = (float*)alloc((size_t)N_NODES * D * 4);        // 51.2 MB
    float* F1       = (float*)alloc((size_t)N_NODES * D * 4);        // 51.2 MB
    unsigned short* P = (unsigned short*)alloc((size_t)N_NODES * D * 2);  // 25.6 MB (hs)
    unsigned short* Q = (unsigned short*)alloc((size_t)N_NODES * D * 2);  // 25.6 MB (agg out)
    unsigned short* Wt = (unsigned short*)alloc((size_t)NLAYERS * D * D * 2);
    int*   degO     = (int*)alloc((size_t)N_NODES * 4);
    int*   degI     = (int*)alloc((size_t)N_NODES * 4);
    int*   row_ptr  = (int*)alloc((size_t)(N_NODES + 1) * 4);
    int*   cursor   = (int*)alloc((size_t)N_NODES * 4);
    int*   col_idx  = (int*)alloc((size_t)N_EDGES * 4);
    float* norm_src = (float*)alloc((size_t)N_NODES * 4);
    float* norm_dst = (float*)alloc((size_t)N_NODES * 4);
    float* stats    = (float*)alloc(8 * 2 * D * 4);
    float* fin      = (float*)alloc(2 * D * 4);
    float* pooled   = (float*)alloc((size_t)NGRAPH * D * 4);
    int*   blksum   = (int*)alloc(128 * 4);

    // ---- CSR build
    hipMemsetAsync(degO, 0, (size_t)N_NODES * 4, stream);
    hipMemsetAsync(degI, 0, (size_t)N_NODES * 4, stream);
    hipMemsetAsync(cursor, 0, (size_t)N_NODES * 4, stream);
    deg_kernel<<<(N_EDGES + 255) / 256, 256, 0, stream>>>(src, dst, degO, degI);
    norm_kernel<<<(N_NODES + 255) / 256, 256, 0, stream>>>(degO, degI, norm_src, norm_dst);
    int nb = (N_NODES + 1023) / 1024;
    scan1_kernel<<<nb, 256, 0, stream>>>(degI, row_ptr, blksum);
    scan2_kernel<<<1, 128, 0, stream>>>(blksum, nb, row_ptr);
    scan3_kernel<<<(N_NODES + 255) / 256, 256, 0, stream>>>(row_ptr, blksum);
    scatter_kernel<<<(N_EDGES + 255) / 256, 256, 0, stream>>>(src, dst, row_ptr, cursor, col_idx);

    // ---- weight + input prep
    wprep_kernel<<<(NLAYERS * D * D + 255) / 256, 256, 0, stream>>>(W, Wt);
    prep_hs_kernel<<<(N_NODES * 32 + 255) / 256, 256, 0, stream>>>(h, norm_src, P);

    // ---- layers
    int gemm_blocks = (N_NODES + 127) / 128;   // 782
    for (int l = 0; l < NLAYERS; ++l) {
        float* G = (l & 1) ? F1 : F0;
        const float* X = (l & 1) ? F0 : F1;
        agg_kernel<<<(N_NODES * 16 + 255) / 256, 256, 0, stream>>>(P, row_ptr, col_idx,
                                                                   norm_dst, Q);
        hipMemsetAsync(stats, 0, 8 * 2 * D * 4, stream);
        gemm_mfma_kernel<<<gemm_blocks, 256, 0, stream>>>(Q, Wt + (size_t)l * D * D,
                                                          b + (size_t)l * D, G, stats, N_NODES);
        bn_finalize_kernel<<<1, 128, 0, stream>>>(stats, gamma + (size_t)l * D,
                                                  beta + (size_t)l * D, fin);
        bn_apply_kernel<<<(N_NODES * 32 + 255) / 256, 256, 0, stream>>>(
            G, X, fin, norm_src, P, l > 0 ? 1 : 0, l < NLAYERS - 1 ? 1 : 0);
    }

    // ---- pooling + head (final x is in F1 for L=4)
    hipMemsetAsync(pooled, 0, (size_t)NGRAPH * D * 4, stream);
    pool_kernel<<<(N_NODES + 127) / 128, 256, 0, stream>>>((NLAYERS & 1) ? F0 : F1, gid, pooled);
    head_kernel<<<4, 256, 0, stream>>>(pooled, Wp, bp, out);
}

// Round 3
// 769.679 us; speedup vs baseline: 2.0233x; 1.1052x over previous
//
#include <hip/hip_runtime.h>

#define N_NODES 100000
#define N_EDGES 1600000
#define D 128
#define NLAYERS 4
#define NGRAPH 100
#define NOUT 10
#define BN_EPS 1e-5f

#define SORT_B 391     // pass blocks: 391 * 4096 >= E
#define NWP 1564       // SORT_B * 4 wave-chunks of 1024

typedef __attribute__((ext_vector_type(8))) short bf16x8;
typedef __attribute__((ext_vector_type(8))) unsigned short u16x8;
typedef __attribute__((ext_vector_type(4))) float f32x4;

static __device__ __forceinline__ unsigned short f2bf(float f) {
    unsigned u = __builtin_bit_cast(unsigned, f);
    unsigned r = (u + 0x7fffu + ((u >> 16) & 1u)) >> 16;
    return (unsigned short)r;
}
static __device__ __forceinline__ float bf2f(unsigned short b) {
    unsigned u = ((unsigned)b) << 16;
    return __builtin_bit_cast(float, u);
}

// ---------------------------------------------------------------- deg_out histogram (atomics kept)
__global__ void hist_src_kernel(const int* __restrict__ src, int* __restrict__ degO) {
    int e = blockIdx.x * blockDim.x + threadIdx.x;
    if (e < N_EDGES) atomicAdd(&degO[src[e]], 1);
}

// ---------------------------------------------------------------- radix sort pass 1 (low 9 bits)
__global__ __launch_bounds__(256) void hist1_kernel(const int* __restrict__ dst,
                                                    int* __restrict__ ph) {
    __shared__ int h[512];
    int t = threadIdx.x;
    h[t] = 0; h[t + 256] = 0;
    __syncthreads();
    int base = blockIdx.x * 4096;
#pragma unroll
    for (int i = 0; i < 16; ++i) {
        int e = base + i * 256 + t;
        if (e < N_EDGES) atomicAdd(&h[dst[e] & 511], 1);
    }
    __syncthreads();
    ph[t * SORT_B + blockIdx.x] = h[t];
    ph[(t + 256) * SORT_B + blockIdx.x] = h[t + 256];
}

__global__ __launch_bounds__(256) void place1_kernel(const int* __restrict__ dst,
        const int* __restrict__ src, const int* __restrict__ ph,
        int* __restrict__ k1, int* __restrict__ v1) {
    __shared__ int cur[512];
    int t = threadIdx.x;
    cur[t] = ph[t * SORT_B + blockIdx.x];
    cur[t + 256] = ph[(t + 256) * SORT_B + blockIdx.x];
    __syncthreads();
    int base = blockIdx.x * 4096;
#pragma unroll
    for (int i = 0; i < 16; ++i) {
        int e = base + i * 256 + t;
        if (e < N_EDGES) {
            int k = dst[e];
            int pos = atomicAdd(&cur[k & 511], 1);
            k1[pos] = k;
            v1[pos] = src[e];
        }
    }
}

// ---------------------------------------------------------------- radix sort pass 2 (high 8 bits, wave-stable)
__global__ __launch_bounds__(256) void hist2_kernel(const int* __restrict__ k1,
                                                    int* __restrict__ ph) {
    __shared__ int h[4 * 256];
    int t = threadIdx.x;
    h[t] = 0; h[t + 256] = 0; h[t + 512] = 0; h[t + 768] = 0;
    __syncthreads();
    int w = t >> 6, lane = t & 63;
    int g = blockIdx.x * 4 + w;
    int base = g * 1024;
#pragma unroll
    for (int r = 0; r < 16; ++r) {
        int e = base + r * 64 + lane;
        if (e < N_EDGES) atomicAdd(&h[w * 256 + (k1[e] >> 9)], 1);
    }
    __syncthreads();
#pragma unroll
    for (int w2 = 0; w2 < 4; ++w2)
        ph[t * NWP + blockIdx.x * 4 + w2] = h[w2 * 256 + t];
}

__global__ __launch_bounds__(256) void place2_kernel(const int* __restrict__ k1,
        const int* __restrict__ v1, const int* __restrict__ ph,
        int* __restrict__ k2, int* __restrict__ col) {
    __shared__ int cur[4 * 256];
    int t = threadIdx.x;
    int w = t >> 6, lane = t & 63;
    int g = blockIdx.x * 4 + w;
#pragma unroll
    for (int w2 = 0; w2 < 4; ++w2)
        cur[w2 * 256 + t] = ph[t * NWP + blockIdx.x * 4 + w2];
    __syncthreads();
    int base = g * 1024;
    for (int r = 0; r < 16; ++r) {
        int e = base + r * 64 + lane;
        int valid = (e < N_EDGES) ? 1 : 0;
        int k = valid ? k1[e] : 0;
        int d = valid ? (k >> 9) : 255;
        unsigned long long mask = ~0ull;
#pragma unroll
        for (int j = 0; j < 8; ++j) {
            unsigned long long bj = __ballot((d >> j) & 1);
            mask &= ((d >> j) & 1) ? bj : ~bj;
        }
        unsigned long long below = mask & ((1ull << lane) - 1ull);
        int rank = __popcll(below);
        int first = __ffsll((long long)mask) - 1;
        int pos_base = 0;
        if (lane == first) pos_base = atomicAdd(&cur[w * 256 + d], __popcll(mask));
        pos_base = __shfl(pos_base, first, 64);
        if (valid) {
            int pos = pos_base + rank;
            k2[pos] = k;
            col[pos] = v1[e];
        }
    }
}

// ---------------------------------------------------------------- generalized scan (exclusive)
__global__ void scanA_kernel(int* __restrict__ data, int* __restrict__ blksum, int n) {
    __shared__ int s[256];
    int t = threadIdx.x;
    int base = blockIdx.x * 2048 + t * 8;
    int v[8]; int sum = 0;
#pragma unroll
    for (int j = 0; j < 8; ++j) { v[j] = (base + j < n) ? data[base + j] : 0; sum += v[j]; }
    s[t] = sum;
    __syncthreads();
    for (int off = 1; off < 256; off <<= 1) {
        int x = 0;
        if (t >= off) x = s[t - off];
        __syncthreads();
        s[t] += x;
        __syncthreads();
    }
    int run = s[t] - sum;
#pragma unroll
    for (int j = 0; j < 8; ++j) { if (base + j < n) data[base + j] = run; run += v[j]; }
    if (t == 255) blksum[blockIdx.x] = s[255];
}

__global__ void scanB_kernel(int* __restrict__ blksum, int nb) {
    __shared__ int s[256];
    int t = threadIdx.x;
    int v = (t < nb) ? blksum[t] : 0;
    s[t] = v;
    __syncthreads();
    for (int off = 1; off < 256; off <<= 1) {
        int x = 0;
        if (t >= off) x = s[t - off];
        __syncthreads();
        s[t] += x;
        __syncthreads();
    }
    if (t < nb) blksum[t] = s[t] - v;
}

__global__ void scanC_kernel(int* __restrict__ data, const int* __restrict__ blksum, int n) {
    int i = blockIdx.x * blockDim.x + threadIdx.x;
    if (i < n) data[i] += blksum[i >> 11];
}

// ---------------------------------------------------------------- row_ptr from sorted keys
__global__ void rowptr_kernel(const int* __restrict__ k2, int* __restrict__ rp) {
    int i = blockIdx.x * blockDim.x + threadIdx.x;
    if (i >= N_EDGES) return;
    int k = k2[i];
    int kprev = (i == 0) ? -1 : k2[i - 1];
    if (k != kprev)
        for (int v = kprev + 1; v <= k; ++v) rp[v] = i;
    if (i == N_EDGES - 1)
        for (int v = k + 1; v <= N_NODES; ++v) rp[v] = N_EDGES;
}

__global__ void norms_kernel(const int* __restrict__ degO, const int* __restrict__ rp,
                             float* __restrict__ norm_src, float* __restrict__ norm_dst) {
    int v = blockIdx.x * blockDim.x + threadIdx.x;
    if (v < N_NODES) {
        norm_src[v] = rsqrtf((float)max(degO[v], 1));
        norm_dst[v] = rsqrtf((float)max(rp[v + 1] - rp[v], 1));
    }
}

// ---------------------------------------------------------------- weight prep (bf16, B^T, XOR-swizzled)
__global__ void wprep_kernel(const float* __restrict__ W, unsigned short* __restrict__ Wt) {
    int i = blockIdx.x * blockDim.x + threadIdx.x;
    if (i >= NLAYERS * D * D) return;
    int l = i >> 14;
    int r = i & (D * D - 1);
    int col = r >> 7;
    int k = r & 127;
    float v = W[(size_t)l * D * D + k * D + col];
    int byteoff = col * 256 + k * 2;
    int swz = byteoff ^ ((col & 7) << 4);
    Wt[(size_t)l * D * D + (swz >> 1)] = f2bf(v);
}

// ---------------------------------------------------------------- prep hs = bf16(h * norm_src)
__global__ void prep_hs_kernel(const float* __restrict__ h, const float* __restrict__ norm_src,
                               unsigned short* __restrict__ hs) {
    int tid = blockIdx.x * blockDim.x + threadIdx.x;
    int v = tid >> 5;
    if (v >= N_NODES) return;
    int c4 = (tid & 31) << 2;
    float ns = norm_src[v];
    float4 hv = *reinterpret_cast<const float4*>(h + (size_t)v * D + c4);
    unsigned short o[4] = {f2bf(hv.x * ns), f2bf(hv.y * ns), f2bf(hv.z * ns), f2bf(hv.w * ns)};
    *reinterpret_cast<ushort4*>(hs + (size_t)v * D + c4) = *reinterpret_cast<ushort4*>(o);
}

// ---------------------------------------------------------------- aggregation (bf16 in/out)
__global__ void agg_kernel(const unsigned short* __restrict__ hs, const int* __restrict__ rp,
                           const int* __restrict__ col_idx, const float* __restrict__ norm_dst,
                           unsigned short* __restrict__ aggb) {
    int tid = blockIdx.x * blockDim.x + threadIdx.x;
    int v = tid >> 4;
    if (v >= N_NODES) return;
    int c8 = (tid & 15) << 3;
    int e0 = rp[v], e1 = rp[v + 1];
    float acc[8] = {0.f, 0.f, 0.f, 0.f, 0.f, 0.f, 0.f, 0.f};
    for (int e = e0; e < e1; ++e) {
        int u = col_idx[e];
        u16x8 hv = *reinterpret_cast<const u16x8*>(hs + (size_t)u * D + c8);
#pragma unroll
        for (int j = 0; j < 8; ++j) acc[j] += bf2f(hv[j]);
    }
    float nd = norm_dst[v];
    unsigned short o[8];
#pragma unroll
    for (int j = 0; j < 8; ++j) o[j] = f2bf(acc[j] * nd);
    *reinterpret_cast<u16x8*>(aggb + (size_t)v * D + c8) = *reinterpret_cast<u16x8*>(o);
}

// ---------------------------------------------------------------- MFMA GEMM + per-block BN partials
__global__ __launch_bounds__(256) void gemm_mfma_kernel(const unsigned short* __restrict__ A,
        const unsigned short* __restrict__ Wt, const float* __restrict__ bl,
        float* __restrict__ outF, float* __restrict__ pstats, int nrows) {
    __shared__ __align__(16) unsigned short sW[D * D];   // 32 KB
    __shared__ float part[4 * 2 * 128];                  // 4 KB
    int t = threadIdx.x;
#pragma unroll
    for (int i = 0; i < 8; ++i) {
        int idx = t + i * 256;
        reinterpret_cast<uint4*>(sW)[idx] = reinterpret_cast<const uint4*>(Wt)[idx];
    }
    __syncthreads();

    int wave = t >> 6;
    int lane = t & 63;
    int l15 = lane & 15;
    int lg = lane >> 4;
    int rowbase = blockIdx.x * 128 + wave * 32;

    f32x4 acc[2][8];
#pragma unroll
    for (int rf = 0; rf < 2; ++rf)
#pragma unroll
        for (int cf = 0; cf < 8; ++cf) acc[rf][cf] = (f32x4){0.f, 0.f, 0.f, 0.f};

#pragma unroll
    for (int ks = 0; ks < 4; ++ks) {
        bf16x8 a[2];
#pragma unroll
        for (int rf = 0; rf < 2; ++rf) {
            int r = rowbase + rf * 16 + l15;
            if (r >= nrows) r = nrows - 1;
            a[rf] = *reinterpret_cast<const bf16x8*>(A + (size_t)r * D + ks * 32 + lg * 8);
        }
#pragma unroll
        for (int cf = 0; cf < 8; ++cf) {
            int col = cf * 16 + l15;
            int byteoff = (col * 256 + ks * 64 + lg * 16) ^ ((col & 7) << 4);
            bf16x8 bfrag = *reinterpret_cast<const bf16x8*>(
                reinterpret_cast<const char*>(sW) + byteoff);
            acc[0][cf] = __builtin_amdgcn_mfma_f32_16x16x32_bf16(a[0], bfrag, acc[0][cf], 0, 0, 0);
            acc[1][cf] = __builtin_amdgcn_mfma_f32_16x16x32_bf16(a[1], bfrag, acc[1][cf], 0, 0, 0);
        }
    }

    // epilogue: bias + store + per-block BN partials (no atomics)
#pragma unroll
    for (int cf = 0; cf < 8; ++cf) {
        int c = cf * 16 + l15;
        float bias = bl[c];
        float s = 0.f, sq = 0.f;
#pragma unroll
        for (int rf = 0; rf < 2; ++rf) {
            int rb = rowbase + rf * 16 + lg * 4;
#pragma unroll
            for (int j = 0; j < 4; ++j) {
                int row = rb + j;
                if (row < nrows) {
                    float val = acc[rf][cf][j] + bias;
                    outF[(size_t)row * D + c] = val;
                    s += val;
                    sq += val * val;
                }
            }
        }
        s += __shfl_xor(s, 16);
        s += __shfl_xor(s, 32);
        sq += __shfl_xor(sq, 16);
        sq += __shfl_xor(sq, 32);
        if (lg == 0) {
            part[wave * 256 + c] = s;
            part[wave * 256 + 128 + c] = sq;
        }
    }
    __syncthreads();
    // t: which = t>>7 (0 sum, 1 sumsq), c = t&127
    float tot = part[0 * 256 + (t >> 7) * 128 + (t & 127)]
              + part[1 * 256 + (t >> 7) * 128 + (t & 127)]
              + part[2 * 256 + (t >> 7) * 128 + (t & 127)]
              + part[3 * 256 + (t >> 7) * 128 + (t & 127)];
    pstats[(size_t)blockIdx.x * 256 + t] = tot;
}

// ---------------------------------------------------------------- BN stat reduction + finalize
__global__ void reduce_pstats_kernel(const float* __restrict__ pstats, float* __restrict__ pstats2,
                                     int nblk) {
    int t = threadIdx.x;
    int bb = blockIdx.x;           // 16 blocks
    int chunk = (nblk + 15) / 16;
    int b0 = bb * chunk, b1 = min(b0 + chunk, nblk);
    float s = 0.f;
    for (int b = b0; b < b1; ++b) s += pstats[(size_t)b * 256 + t];
    pstats2[bb * 256 + t] = s;
}

__global__ void bn_finalize_kernel(const float* __restrict__ pstats2, const float* __restrict__ gamma,
                                   const float* __restrict__ beta, float* __restrict__ fin) {
    int c = threadIdx.x;   // 128
    float s = 0.f, sq = 0.f;
#pragma unroll
    for (int i = 0; i < 16; ++i) {
        s += pstats2[i * 256 + c];
        sq += pstats2[i * 256 + 128 + c];
    }
    float mu = s * (1.f / N_NODES);
    float var = sq * (1.f / N_NODES) - mu * mu;
    float sc = rsqrtf(var + BN_EPS) * gamma[c];
    fin[c] = sc;
    fin[D + c] = beta[c] - mu * sc;
}

// ---------------------------------------------------------------- BN apply (+relu,+residual) in-place
__global__ void bn_apply_kernel(float* __restrict__ g, const float* __restrict__ xres,
                                const float* __restrict__ fin, const float* __restrict__ norm_src,
                                unsigned short* __restrict__ hs, int residual, int write_hs) {
    int tid = blockIdx.x * blockDim.x + threadIdx.x;
    int v = tid >> 5;
    if (v >= N_NODES) return;
    int c4 = (tid & 31) << 2;
    float4 hv = *reinterpret_cast<float4*>(g + (size_t)v * D + c4);
    float4 sc = *reinterpret_cast<const float4*>(fin + c4);
    float4 sh = *reinterpret_cast<const float4*>(fin + D + c4);
    float o[4];
    o[0] = fmaxf(fmaf(hv.x, sc.x, sh.x), 0.f);
    o[1] = fmaxf(fmaf(hv.y, sc.y, sh.y), 0.f);
    o[2] = fmaxf(fmaf(hv.z, sc.z, sh.z), 0.f);
    o[3] = fmaxf(fmaf(hv.w, sc.w, sh.w), 0.f);
    if (residual) {
        float4 xv = *reinterpret_cast<const float4*>(xres + (size_t)v * D + c4);
        o[0] += xv.x; o[1] += xv.y; o[2] += xv.z; o[3] += xv.w;
    }
    float4 ov = {o[0], o[1], o[2], o[3]};
    *reinterpret_cast<float4*>(g + (size_t)v * D + c4) = ov;
    if (write_hs) {
        float ns = norm_src[v];
        unsigned short ob[4] = {f2bf(o[0] * ns), f2bf(o[1] * ns), f2bf(o[2] * ns), f2bf(o[3] * ns)};
        *reinterpret_cast<ushort4*>(hs + (size_t)v * D + c4) = *reinterpret_cast<ushort4*>(ob);
    }
}

// ---------------------------------------------------------------- pooling + head
__global__ void pool_kernel(const float* __restrict__ h, const int* __restrict__ gid,
                            float* __restrict__ pooled) {
    int base = blockIdx.x * 128;
    int c4 = (threadIdx.x & 31) << 2;
    int sub = threadIdx.x >> 5;
    int r0 = base + sub * 16;
    if (r0 >= N_NODES) return;
    int r1 = min(r0 + 16, N_NODES);
    int gcur = gid[r0];
    float ax = 0.f, ay = 0.f, az = 0.f, aw = 0.f;
    for (int row = r0; row < r1; ++row) {
        int g = gid[row];
        const float4 hv = *reinterpret_cast<const float4*>(h + (size_t)row * D + c4);
        if (g != gcur) {
            atomicAdd(&pooled[gcur * D + c4 + 0], ax);
            atomicAdd(&pooled[gcur * D + c4 + 1], ay);
            atomicAdd(&pooled[gcur * D + c4 + 2], az);
            atomicAdd(&pooled[gcur * D + c4 + 3], aw);
            ax = ay = az = aw = 0.f;
            gcur = g;
        }
        ax += hv.x; ay += hv.y; az += hv.z; aw += hv.w;
    }
    atomicAdd(&pooled[gcur * D + c4 + 0], ax);
    atomicAdd(&pooled[gcur * D + c4 + 1], ay);
    atomicAdd(&pooled[gcur * D + c4 + 2], az);
    atomicAdd(&pooled[gcur * D + c4 + 3], aw);
}

__global__ void head_kernel(const float* __restrict__ pooled, const float* __restrict__ Wp,
                            const float* __restrict__ bp, float* __restrict__ out) {
    int tid = blockIdx.x * blockDim.x + threadIdx.x;
    if (tid >= NGRAPH * NOUT) return;
    int g = tid / NOUT, o = tid % NOUT;
    float sum = bp[o];
    for (int k = 0; k < D; ++k) sum = fmaf(pooled[g * D + k], Wp[k * NOUT + o], sum);
    out[tid] = sum;
}

// ----------------------------------------------------------------
extern "C" void kernel_launch(void* const* d_in, const int* in_sizes, int n_in,
                              void* d_out, int out_size, void* d_ws, size_t ws_size,
                              hipStream_t stream) {
    const float* h     = (const float*)d_in[0];
    const float* W     = (const float*)d_in[1];
    const float* b     = (const float*)d_in[2];
    const float* gamma = (const float*)d_in[3];
    const float* beta  = (const float*)d_in[4];
    const float* Wp    = (const float*)d_in[5];
    const float* bp    = (const float*)d_in[6];
    const int*   src   = (const int*)d_in[7];
    const int*   dst   = (const int*)d_in[8];
    const int*   gid   = (const int*)d_in[9];
    float* out = (float*)d_out;

    char* ws = (char*)d_ws;
    size_t off = 0;
    auto alloc = [&](size_t bytes) { char* p = ws + off; off = (off + bytes + 511) & ~(size_t)511; return p; };
    float* F0       = (float*)alloc((size_t)N_NODES * D * 4);            // 51.2 MB
    float* F1       = (float*)alloc((size_t)N_NODES * D * 4);            // 51.2 MB
    unsigned short* P = (unsigned short*)alloc((size_t)N_NODES * D * 2); // hs
    unsigned short* Q = (unsigned short*)alloc((size_t)N_NODES * D * 2); // agg out
    unsigned short* Wt = (unsigned short*)alloc((size_t)NLAYERS * D * D * 2);
    int*   degO     = (int*)alloc((size_t)N_NODES * 4);
    int*   row_ptr  = (int*)alloc((size_t)(N_NODES + 1) * 4);
    int*   col_idx  = (int*)alloc((size_t)N_EDGES * 4);
    float* norm_src = (float*)alloc((size_t)N_NODES * 4);
    float* norm_dst = (float*)alloc((size_t)N_NODES * 4);
    int*   ph1      = (int*)alloc((size_t)512 * SORT_B * 4);             // 801 KB
    int*   ph2      = (int*)alloc((size_t)256 * NWP * 4);                // 1.6 MB
    int*   blksum   = (int*)alloc(256 * 4);
    float* pstats   = (float*)alloc((size_t)782 * 256 * 4);              // 800 KB
    float* pstats2  = (float*)alloc((size_t)16 * 256 * 4);
    float* fin      = (float*)alloc(2 * D * 4);
    float* pooled   = (float*)alloc((size_t)NGRAPH * D * 4);

    // sort scratch aliased into F0 / Q (dead until first GEMM / first agg)
    int* k1 = (int*)F0;
    int* v1 = (int*)F0 + N_EDGES;
    int* k2 = (int*)Q;

    // ---- deg_out histogram (needed for norm_src)
    hipMemsetAsync(degO, 0, (size_t)N_NODES * 4, stream);
    hist_src_kernel<<<(N_EDGES + 255) / 256, 256, 0, stream>>>(src, degO);

    // ---- radix sort by dst: pass 1 (low 9 bits)
    hist1_kernel<<<SORT_B, 256, 0, stream>>>(dst, ph1);
    int n1 = 512 * SORT_B;
    scanA_kernel<<<(n1 + 2047) / 2048, 256, 0, stream>>>(ph1, blksum, n1);
    scanB_kernel<<<1, 256, 0, stream>>>(blksum, (n1 + 2047) / 2048);
    scanC_kernel<<<(n1 + 255) / 256, 256, 0, stream>>>(ph1, blksum, n1);
    place1_kernel<<<SORT_B, 256, 0, stream>>>(dst, src, ph1, k1, v1);

    // ---- pass 2 (high 8 bits, wave-stable)
    hist2_kernel<<<SORT_B, 256, 0, stream>>>(k1, ph2);
    int n2 = 256 * NWP;
    scanA_kernel<<<(n2 + 2047) / 2048, 256, 0, stream>>>(ph2, blksum, n2);
    scanB_kernel<<<1, 256, 0, stream>>>(blksum, (n2 + 2047) / 2048);
    scanC_kernel<<<(n2 + 255) / 256, 256, 0, stream>>>(ph2, blksum, n2);
    place2_kernel<<<SORT_B, 256, 0, stream>>>(k1, v1, ph2, k2, col_idx);

    // ---- row_ptr + norms
    rowptr_kernel<<<(N_EDGES + 255) / 256, 256, 0, stream>>>(k2, row_ptr);
    norms_kernel<<<(N_NODES + 255) / 256, 256, 0, stream>>>(degO, row_ptr, norm_src, norm_dst);

    // ---- weight + input prep
    wprep_kernel<<<(NLAYERS * D * D + 255) / 256, 256, 0, stream>>>(W, Wt);
    prep_hs_kernel<<<(N_NODES * 32 + 255) / 256, 256, 0, stream>>>(h, norm_src, P);

    // ---- layers
    int gemm_blocks = (N_NODES + 127) / 128;   // 782
    for (int l = 0; l < NLAYERS; ++l) {
        float* G = (l & 1) ? F1 : F0;
        const float* X = (l & 1) ? F0 : F1;
        agg_kernel<<<(N_NODES * 16 + 255) / 256, 256, 0, stream>>>(P, row_ptr, col_idx,
                                                                   norm_dst, Q);
        gemm_mfma_kernel<<<gemm_blocks, 256, 0, stream>>>(Q, Wt + (size_t)l * D * D,
                                                          b + (size_t)l * D, G, pstats, N_NODES);
        reduce_pstats_kernel<<<16, 256, 0, stream>>>(pstats, pstats2, gemm_blocks);
        bn_finalize_kernel<<<1, 128, 0, stream>>>(pstats2, gamma + (size_t)l * D,
                                                  beta + (size_t)l * D, fin);
        bn_apply_kernel<<<(N_NODES * 32 + 255) / 256, 256, 0, stream>>>(
            G, X, fin, norm_src, P, l > 0 ? 1 : 0, l < NLAYERS - 1 ? 1 : 0);
    }

    // ---- pooling + head (final x in F1)
    hipMemsetAsync(pooled, 0, (size_t)NGRAPH * D * 4, stream);
    pool_kernel<<<(N_NODES + 127) / 128, 256, 0, stream>>>(F1, gid, pooled);
    head_kernel<<<4, 256, 0, stream>>>(pooled, Wp, bp, out);
}

// Round 4
// 674.227 us; speedup vs baseline: 2.3097x; 1.1416x over previous
//
#include <hip/hip_runtime.h>

#define N_NODES 100000
#define N_EDGES 1600000
#define D 128
#define NLAYERS 4
#define NGRAPH 100
#define NOUT 10
#define BN_EPS 1e-5f

#define SORT_B 391     // pass blocks: 391 * 4096 >= E
#define NWP 1564       // SORT_B * 4 wave-chunks of 1024

typedef __attribute__((ext_vector_type(8))) short bf16x8;
typedef __attribute__((ext_vector_type(8))) unsigned short u16x8;
typedef __attribute__((ext_vector_type(4))) float f32x4;

static __device__ __forceinline__ unsigned short f2bf(float f) {
    unsigned u = __builtin_bit_cast(unsigned, f);
    unsigned r = (u + 0x7fffu + ((u >> 16) & 1u)) >> 16;
    return (unsigned short)r;
}
static __device__ __forceinline__ float bf2f(unsigned short b) {
    unsigned u = ((unsigned)b) << 16;
    return __builtin_bit_cast(float, u);
}

// ---------------------------------------------------------------- radix pass 1 hist + deg_out hist (fused)
__global__ __launch_bounds__(256) void hist1_kernel(const int* __restrict__ dst,
                                                    const int* __restrict__ src,
                                                    int* __restrict__ ph,
                                                    int* __restrict__ degO) {
    __shared__ int h[512];
    int t = threadIdx.x;
    h[t] = 0; h[t + 256] = 0;
    __syncthreads();
    int base = blockIdx.x * 4096;
#pragma unroll
    for (int i = 0; i < 16; ++i) {
        int e = base + i * 256 + t;
        if (e < N_EDGES) {
            atomicAdd(&h[dst[e] & 511], 1);
            atomicAdd(&degO[src[e]], 1);
        }
    }
    __syncthreads();
    ph[t * SORT_B + blockIdx.x] = h[t];
    ph[(t + 256) * SORT_B + blockIdx.x] = h[t + 256];
}

__global__ __launch_bounds__(256) void place1_kernel(const int* __restrict__ dst,
        const int* __restrict__ src, const int* __restrict__ ph,
        int* __restrict__ k1, int* __restrict__ v1) {
    __shared__ int cur[512];
    int t = threadIdx.x;
    cur[t] = ph[t * SORT_B + blockIdx.x];
    cur[t + 256] = ph[(t + 256) * SORT_B + blockIdx.x];
    __syncthreads();
    int base = blockIdx.x * 4096;
#pragma unroll
    for (int i = 0; i < 16; ++i) {
        int e = base + i * 256 + t;
        if (e < N_EDGES) {
            int k = dst[e];
            int pos = atomicAdd(&cur[k & 511], 1);
            k1[pos] = k;
            v1[pos] = src[e];
        }
    }
}

// ---------------------------------------------------------------- radix pass 2 (high 8 bits, wave-stable)
__global__ __launch_bounds__(256) void hist2_kernel(const int* __restrict__ k1,
                                                    int* __restrict__ ph) {
    __shared__ int h[4 * 256];
    int t = threadIdx.x;
    h[t] = 0; h[t + 256] = 0; h[t + 512] = 0; h[t + 768] = 0;
    __syncthreads();
    int w = t >> 6, lane = t & 63;
    int g = blockIdx.x * 4 + w;
    int base = g * 1024;
#pragma unroll
    for (int r = 0; r < 16; ++r) {
        int e = base + r * 64 + lane;
        if (e < N_EDGES) atomicAdd(&h[w * 256 + (k1[e] >> 9)], 1);
    }
    __syncthreads();
#pragma unroll
    for (int w2 = 0; w2 < 4; ++w2)
        ph[t * NWP + blockIdx.x * 4 + w2] = h[w2 * 256 + t];
}

__global__ __launch_bounds__(256) void place2_kernel(const int* __restrict__ k1,
        const int* __restrict__ v1, const int* __restrict__ ph,
        int* __restrict__ k2, int* __restrict__ col) {
    __shared__ int cur[4 * 256];
    int t = threadIdx.x;
    int w = t >> 6, lane = t & 63;
    int g = blockIdx.x * 4 + w;
#pragma unroll
    for (int w2 = 0; w2 < 4; ++w2)
        cur[w2 * 256 + t] = ph[t * NWP + blockIdx.x * 4 + w2];
    __syncthreads();
    int base = g * 1024;
    for (int r = 0; r < 16; ++r) {
        int e = base + r * 64 + lane;
        int valid = (e < N_EDGES) ? 1 : 0;
        int k = valid ? k1[e] : 0;
        int d = valid ? (k >> 9) : 255;
        unsigned long long mask = ~0ull;
#pragma unroll
        for (int j = 0; j < 8; ++j) {
            unsigned long long bj = __ballot((d >> j) & 1);
            mask &= ((d >> j) & 1) ? bj : ~bj;
        }
        unsigned long long below = mask & ((1ull << lane) - 1ull);
        int rank = __popcll(below);
        int first = __ffsll((long long)mask) - 1;
        int pos_base = 0;
        if (lane == first) pos_base = atomicAdd(&cur[w * 256 + d], __popcll(mask));
        pos_base = __shfl(pos_base, first, 64);
        if (valid) {
            int pos = pos_base + rank;
            k2[pos] = k;
            col[pos] = v1[e];
        }
    }
}

// ---------------------------------------------------------------- generalized scan (exclusive)
__global__ void scanA_kernel(int* __restrict__ data, int* __restrict__ blksum, int n) {
    __shared__ int s[256];
    int t = threadIdx.x;
    int base = blockIdx.x * 2048 + t * 8;
    int v[8]; int sum = 0;
#pragma unroll
    for (int j = 0; j < 8; ++j) { v[j] = (base + j < n) ? data[base + j] : 0; sum += v[j]; }
    s[t] = sum;
    __syncthreads();
    for (int off = 1; off < 256; off <<= 1) {
        int x = 0;
        if (t >= off) x = s[t - off];
        __syncthreads();
        s[t] += x;
        __syncthreads();
    }
    int run = s[t] - sum;
#pragma unroll
    for (int j = 0; j < 8; ++j) { if (base + j < n) data[base + j] = run; run += v[j]; }
    if (t == 255) blksum[blockIdx.x] = s[255];
}

__global__ void scanB_kernel(int* __restrict__ blksum, int nb) {
    __shared__ int s[256];
    int t = threadIdx.x;
    int v = (t < nb) ? blksum[t] : 0;
    s[t] = v;
    __syncthreads();
    for (int off = 1; off < 256; off <<= 1) {
        int x = 0;
        if (t >= off) x = s[t - off];
        __syncthreads();
        s[t] += x;
        __syncthreads();
    }
    if (t < nb) blksum[t] = s[t] - v;
}

__global__ void scanC_kernel(int* __restrict__ data, const int* __restrict__ blksum, int n) {
    int i = blockIdx.x * blockDim.x + threadIdx.x;
    if (i < n) data[i] += blksum[i >> 11];
}

// ---------------------------------------------------------------- row_ptr from sorted keys
__global__ void rowptr_kernel(const int* __restrict__ k2, int* __restrict__ rp) {
    int i = blockIdx.x * blockDim.x + threadIdx.x;
    if (i >= N_EDGES) return;
    int k = k2[i];
    int kprev = (i == 0) ? -1 : k2[i - 1];
    if (k != kprev)
        for (int v = kprev + 1; v <= k; ++v) rp[v] = i;
    if (i == N_EDGES - 1)
        for (int v = k + 1; v <= N_NODES; ++v) rp[v] = N_EDGES;
}

__global__ void norms_kernel(const int* __restrict__ degO, const int* __restrict__ rp,
                             float* __restrict__ norm_src, float* __restrict__ norm_dst) {
    int v = blockIdx.x * blockDim.x + threadIdx.x;
    if (v < N_NODES) {
        norm_src[v] = rsqrtf((float)max(degO[v], 1));
        norm_dst[v] = rsqrtf((float)max(rp[v + 1] - rp[v], 1));
    }
}

// ---------------------------------------------------------------- weight prep (bf16, B^T, XOR-swizzled)
__global__ void wprep_kernel(const float* __restrict__ W, unsigned short* __restrict__ Wt) {
    int i = blockIdx.x * blockDim.x + threadIdx.x;
    if (i >= NLAYERS * D * D) return;
    int l = i >> 14;
    int r = i & (D * D - 1);
    int col = r >> 7;
    int k = r & 127;
    float v = W[(size_t)l * D * D + k * D + col];
    int byteoff = col * 256 + k * 2;
    int swz = byteoff ^ ((col & 7) << 4);
    Wt[(size_t)l * D * D + (swz >> 1)] = f2bf(v);
}

// ---------------------------------------------------------------- prep hs = bf16(h * norm_src)
__global__ void prep_hs_kernel(const float* __restrict__ h, const float* __restrict__ norm_src,
                               unsigned short* __restrict__ hs) {
    int tid = blockIdx.x * blockDim.x + threadIdx.x;
    int v = tid >> 5;
    if (v >= N_NODES) return;
    int c4 = (tid & 31) << 2;
    float ns = norm_src[v];
    float4 hv = *reinterpret_cast<const float4*>(h + (size_t)v * D + c4);
    unsigned short o[4] = {f2bf(hv.x * ns), f2bf(hv.y * ns), f2bf(hv.z * ns), f2bf(hv.w * ns)};
    *reinterpret_cast<ushort4*>(hs + (size_t)v * D + c4) = *reinterpret_cast<ushort4*>(o);
}

// ---------------------------------------------------------------- aggregation (bf16 in/out, 4x unrolled for MLP)
__global__ __launch_bounds__(256) void agg_kernel(const unsigned short* __restrict__ hs,
                           const int* __restrict__ rp,
                           const int* __restrict__ col_idx, const float* __restrict__ norm_dst,
                           unsigned short* __restrict__ aggb) {
    int tid = blockIdx.x * blockDim.x + threadIdx.x;
    int v = tid >> 4;
    if (v >= N_NODES) return;
    int c8 = (tid & 15) << 3;
    int e0 = rp[v], e1 = rp[v + 1];
    float acc[8] = {0.f, 0.f, 0.f, 0.f, 0.f, 0.f, 0.f, 0.f};
    int e = e0;
    for (; e + 4 <= e1; e += 4) {
        int u0 = col_idx[e + 0];
        int u1 = col_idx[e + 1];
        int u2 = col_idx[e + 2];
        int u3 = col_idx[e + 3];
        u16x8 h0 = *reinterpret_cast<const u16x8*>(hs + (size_t)u0 * D + c8);
        u16x8 h1 = *reinterpret_cast<const u16x8*>(hs + (size_t)u1 * D + c8);
        u16x8 h2 = *reinterpret_cast<const u16x8*>(hs + (size_t)u2 * D + c8);
        u16x8 h3 = *reinterpret_cast<const u16x8*>(hs + (size_t)u3 * D + c8);
#pragma unroll
        for (int j = 0; j < 8; ++j)
            acc[j] += (bf2f(h0[j]) + bf2f(h1[j])) + (bf2f(h2[j]) + bf2f(h3[j]));
    }
    for (; e < e1; ++e) {
        int u = col_idx[e];
        u16x8 hv = *reinterpret_cast<const u16x8*>(hs + (size_t)u * D + c8);
#pragma unroll
        for (int j = 0; j < 8; ++j) acc[j] += bf2f(hv[j]);
    }
    float nd = norm_dst[v];
    unsigned short o[8];
#pragma unroll
    for (int j = 0; j < 8; ++j) o[j] = f2bf(acc[j] * nd);
    *reinterpret_cast<u16x8*>(aggb + (size_t)v * D + c8) = *reinterpret_cast<u16x8*>(o);
}

// ---------------------------------------------------------------- MFMA GEMM (bf16 out) + per-block BN partials
__global__ __launch_bounds__(256) void gemm_mfma_kernel(const unsigned short* __restrict__ A,
        const unsigned short* __restrict__ Wt, const float* __restrict__ bl,
        unsigned short* __restrict__ outB, float* __restrict__ pstats, int nrows) {
    __shared__ __align__(16) unsigned short sW[D * D];   // 32 KB
    __shared__ float part[4 * 2 * 128];                  // 4 KB
    int t = threadIdx.x;
#pragma unroll
    for (int i = 0; i < 8; ++i) {
        int idx = t + i * 256;
        reinterpret_cast<uint4*>(sW)[idx] = reinterpret_cast<const uint4*>(Wt)[idx];
    }
    __syncthreads();

    int wave = t >> 6;
    int lane = t & 63;
    int l15 = lane & 15;
    int lg = lane >> 4;
    int rowbase = blockIdx.x * 128 + wave * 32;

    f32x4 acc[2][8];
#pragma unroll
    for (int rf = 0; rf < 2; ++rf)
#pragma unroll
        for (int cf = 0; cf < 8; ++cf) acc[rf][cf] = (f32x4){0.f, 0.f, 0.f, 0.f};

#pragma unroll
    for (int ks = 0; ks < 4; ++ks) {
        bf16x8 a[2];
#pragma unroll
        for (int rf = 0; rf < 2; ++rf) {
            int r = rowbase + rf * 16 + l15;
            if (r >= nrows) r = nrows - 1;
            a[rf] = *reinterpret_cast<const bf16x8*>(A + (size_t)r * D + ks * 32 + lg * 8);
        }
#pragma unroll
        for (int cf = 0; cf < 8; ++cf) {
            int col = cf * 16 + l15;
            int byteoff = (col * 256 + ks * 64 + lg * 16) ^ ((col & 7) << 4);
            bf16x8 bfrag = *reinterpret_cast<const bf16x8*>(
                reinterpret_cast<const char*>(sW) + byteoff);
            acc[0][cf] = __builtin_amdgcn_mfma_f32_16x16x32_bf16(a[0], bfrag, acc[0][cf], 0, 0, 0);
            acc[1][cf] = __builtin_amdgcn_mfma_f32_16x16x32_bf16(a[1], bfrag, acc[1][cf], 0, 0, 0);
        }
    }

    // epilogue: bias + bf16 store + per-block BN partials (fp32, pre-rounding)
#pragma unroll
    for (int cf = 0; cf < 8; ++cf) {
        int c = cf * 16 + l15;
        float bias = bl[c];
        float s = 0.f, sq = 0.f;
#pragma unroll
        for (int rf = 0; rf < 2; ++rf) {
            int rb = rowbase + rf * 16 + lg * 4;
#pragma unroll
            for (int j = 0; j < 4; ++j) {
                int row = rb + j;
                if (row < nrows) {
                    float val = acc[rf][cf][j] + bias;
                    outB[(size_t)row * D + c] = f2bf(val);
                    s += val;
                    sq += val * val;
                }
            }
        }
        s += __shfl_xor(s, 16);
        s += __shfl_xor(s, 32);
        sq += __shfl_xor(sq, 16);
        sq += __shfl_xor(sq, 32);
        if (lg == 0) {
            part[wave * 256 + c] = s;
            part[wave * 256 + 128 + c] = sq;
        }
    }
    __syncthreads();
    float tot = part[0 * 256 + (t >> 7) * 128 + (t & 127)]
              + part[1 * 256 + (t >> 7) * 128 + (t & 127)]
              + part[2 * 256 + (t >> 7) * 128 + (t & 127)]
              + part[3 * 256 + (t >> 7) * 128 + (t & 127)];
    pstats[(size_t)blockIdx.x * 256 + t] = tot;
}

// ---------------------------------------------------------------- BN stat reduction + finalize
__global__ void reduce_pstats_kernel(const float* __restrict__ pstats, float* __restrict__ pstats2,
                                     int nblk) {
    int t = threadIdx.x;
    int bb = blockIdx.x;           // 16 blocks
    int chunk = (nblk + 15) / 16;
    int b0 = bb * chunk, b1 = min(b0 + chunk, nblk);
    float s = 0.f;
    for (int b = b0; b < b1; ++b) s += pstats[(size_t)b * 256 + t];
    pstats2[bb * 256 + t] = s;
}

__global__ void bn_finalize_kernel(const float* __restrict__ pstats2, const float* __restrict__ gamma,
                                   const float* __restrict__ beta, float* __restrict__ fin) {
    int c = threadIdx.x;   // 128
    float s = 0.f, sq = 0.f;
#pragma unroll
    for (int i = 0; i < 16; ++i) {
        s += pstats2[i * 256 + c];
        sq += pstats2[i * 256 + 128 + c];
    }
    float mu = s * (1.f / N_NODES);
    float var = sq * (1.f / N_NODES) - mu * mu;
    float sc = rsqrtf(var + BN_EPS) * gamma[c];
    fin[c] = sc;
    fin[D + c] = beta[c] - mu * sc;
}

// ---------------------------------------------------------------- BN apply (+relu,+residual), all bf16 I/O
__global__ __launch_bounds__(256) void bn_apply_kernel(const unsigned short* __restrict__ G,
                                const unsigned short* __restrict__ Xres,
                                const float* __restrict__ fin, const float* __restrict__ norm_src,
                                unsigned short* __restrict__ Hout, unsigned short* __restrict__ hs,
                                int residual, int write_hs) {
    int tid = blockIdx.x * blockDim.x + threadIdx.x;
    int v = tid >> 4;
    if (v >= N_NODES) return;
    int c8 = (tid & 15) << 3;
    u16x8 gv = *reinterpret_cast<const u16x8*>(G + (size_t)v * D + c8);
    float4 sc0 = *reinterpret_cast<const float4*>(fin + c8);
    float4 sc1 = *reinterpret_cast<const float4*>(fin + c8 + 4);
    float4 sh0 = *reinterpret_cast<const float4*>(fin + D + c8);
    float4 sh1 = *reinterpret_cast<const float4*>(fin + D + c8 + 4);
    float sc[8] = {sc0.x, sc0.y, sc0.z, sc0.w, sc1.x, sc1.y, sc1.z, sc1.w};
    float sh[8] = {sh0.x, sh0.y, sh0.z, sh0.w, sh1.x, sh1.y, sh1.z, sh1.w};
    float o[8];
#pragma unroll
    for (int j = 0; j < 8; ++j) o[j] = fmaxf(fmaf(bf2f(gv[j]), sc[j], sh[j]), 0.f);
    if (residual) {
        u16x8 xv = *reinterpret_cast<const u16x8*>(Xres + (size_t)v * D + c8);
#pragma unroll
        for (int j = 0; j < 8; ++j) o[j] += bf2f(xv[j]);
    }
    unsigned short ob[8];
#pragma unroll
    for (int j = 0; j < 8; ++j) ob[j] = f2bf(o[j]);
    *reinterpret_cast<u16x8*>(Hout + (size_t)v * D + c8) = *reinterpret_cast<u16x8*>(ob);
    if (write_hs) {
        float ns = norm_src[v];
        unsigned short pb[8];
#pragma unroll
        for (int j = 0; j < 8; ++j) pb[j] = f2bf(o[j] * ns);
        *reinterpret_cast<u16x8*>(hs + (size_t)v * D + c8) = *reinterpret_cast<u16x8*>(pb);
    }
}

// ---------------------------------------------------------------- pooling (bf16 in) + head
__global__ __launch_bounds__(256) void pool_kernel(const unsigned short* __restrict__ h,
                            const int* __restrict__ gid,
                            float* __restrict__ pooled) {
    int base = blockIdx.x * 1024;          // 16 row-groups x 64 rows
    int c8 = (threadIdx.x & 15) << 3;
    int sub = threadIdx.x >> 4;            // 0..15
    int r0 = base + sub * 64;
    if (r0 >= N_NODES) return;
    int r1 = min(r0 + 64, N_NODES);
    int gcur = gid[r0];
    float a[8] = {0.f, 0.f, 0.f, 0.f, 0.f, 0.f, 0.f, 0.f};
    for (int row = r0; row < r1; ++row) {
        int g = gid[row];
        u16x8 hv = *reinterpret_cast<const u16x8*>(h + (size_t)row * D + c8);
        if (g != gcur) {
#pragma unroll
            for (int j = 0; j < 8; ++j) { atomicAdd(&pooled[gcur * D + c8 + j], a[j]); a[j] = 0.f; }
            gcur = g;
        }
#pragma unroll
        for (int j = 0; j < 8; ++j) a[j] += bf2f(hv[j]);
    }
#pragma unroll
    for (int j = 0; j < 8; ++j) atomicAdd(&pooled[gcur * D + c8 + j], a[j]);
}

__global__ void head_kernel(const float* __restrict__ pooled, const float* __restrict__ Wp,
                            const float* __restrict__ bp, float* __restrict__ out) {
    int tid = blockIdx.x * blockDim.x + threadIdx.x;
    if (tid >= NGRAPH * NOUT) return;
    int g = tid / NOUT, o = tid % NOUT;
    float sum = bp[o];
    for (int k = 0; k < D; ++k) sum = fmaf(pooled[g * D + k], Wp[k * NOUT + o], sum);
    out[tid] = sum;
}

// ----------------------------------------------------------------
extern "C" void kernel_launch(void* const* d_in, const int* in_sizes, int n_in,
                              void* d_out, int out_size, void* d_ws, size_t ws_size,
                              hipStream_t stream) {
    const float* h     = (const float*)d_in[0];
    const float* W     = (const float*)d_in[1];
    const float* b     = (const float*)d_in[2];
    const float* gamma = (const float*)d_in[3];
    const float* beta  = (const float*)d_in[4];
    const float* Wp    = (const float*)d_in[5];
    const float* bp    = (const float*)d_in[6];
    const int*   src   = (const int*)d_in[7];
    const int*   dst   = (const int*)d_in[8];
    const int*   gid   = (const int*)d_in[9];
    float* out = (float*)d_out;

    char* ws = (char*)d_ws;
    size_t off = 0;
    auto alloc = [&](size_t bytes) { char* p = ws + off; off = (off + bytes + 511) & ~(size_t)511; return p; };
    unsigned short* Hb0 = (unsigned short*)alloc((size_t)N_NODES * D * 2);  // 25.6 MB h ping
    unsigned short* Hb1 = (unsigned short*)alloc((size_t)N_NODES * D * 2);  // 25.6 MB h pong
    unsigned short* Gb  = (unsigned short*)alloc((size_t)N_NODES * D * 2);  // gemm out
    unsigned short* P   = (unsigned short*)alloc((size_t)N_NODES * D * 2);  // hs (h * norm_src)
    unsigned short* Q   = (unsigned short*)alloc((size_t)N_NODES * D * 2);  // agg out
    unsigned short* Wt  = (unsigned short*)alloc((size_t)NLAYERS * D * D * 2);
    int*   degO     = (int*)alloc((size_t)N_NODES * 4);
    int*   row_ptr  = (int*)alloc((size_t)(N_NODES + 1) * 4);
    int*   col_idx  = (int*)alloc((size_t)N_EDGES * 4);
    float* norm_src = (float*)alloc((size_t)N_NODES * 4);
    float* norm_dst = (float*)alloc((size_t)N_NODES * 4);
    int*   ph1      = (int*)alloc((size_t)512 * SORT_B * 4);
    int*   ph2      = (int*)alloc((size_t)256 * NWP * 4);
    int*   blksum   = (int*)alloc(256 * 4);
    float* pstats   = (float*)alloc((size_t)782 * 256 * 4);
    float* pstats2  = (float*)alloc((size_t)16 * 256 * 4);
    float* fin      = (float*)alloc(2 * D * 4);
    float* pooled   = (float*)alloc((size_t)NGRAPH * D * 4);

    // sort scratch aliased into layer buffers (dead until after sort)
    int* k1 = (int*)Hb0;               // 6.4 MB
    int* v1 = (int*)Hb0 + N_EDGES;     // 6.4 MB (12.8 <= 25.6 MB)
    int* k2 = (int*)Q;                 // 6.4 MB

    // ---- radix sort by dst, pass 1 (low 9 bits) + deg_out histogram fused
    hipMemsetAsync(degO, 0, (size_t)N_NODES * 4, stream);
    hist1_kernel<<<SORT_B, 256, 0, stream>>>(dst, src, ph1, degO);
    int n1 = 512 * SORT_B;
    scanA_kernel<<<(n1 + 2047) / 2048, 256, 0, stream>>>(ph1, blksum, n1);
    scanB_kernel<<<1, 256, 0, stream>>>(blksum, (n1 + 2047) / 2048);
    scanC_kernel<<<(n1 + 255) / 256, 256, 0, stream>>>(ph1, blksum, n1);
    place1_kernel<<<SORT_B, 256, 0, stream>>>(dst, src, ph1, k1, v1);

    // ---- pass 2 (high 8 bits, wave-stable)
    hist2_kernel<<<SORT_B, 256, 0, stream>>>(k1, ph2);
    int n2 = 256 * NWP;
    scanA_kernel<<<(n2 + 2047) / 2048, 256, 0, stream>>>(ph2, blksum, n2);
    scanB_kernel<<<1, 256, 0, stream>>>(blksum, (n2 + 2047) / 2048);
    scanC_kernel<<<(n2 + 255) / 256, 256, 0, stream>>>(ph2, blksum, n2);
    place2_kernel<<<SORT_B, 256, 0, stream>>>(k1, v1, ph2, k2, col_idx);

    // ---- row_ptr + norms
    rowptr_kernel<<<(N_EDGES + 255) / 256, 256, 0, stream>>>(k2, row_ptr);
    norms_kernel<<<(N_NODES + 255) / 256, 256, 0, stream>>>(degO, row_ptr, norm_src, norm_dst);

    // ---- weight + input prep
    wprep_kernel<<<(NLAYERS * D * D + 255) / 256, 256, 0, stream>>>(W, Wt);
    prep_hs_kernel<<<(N_NODES * 32 + 255) / 256, 256, 0, stream>>>(h, norm_src, P);

    // ---- layers (h chain in bf16: l writes Hb[l&1], residual reads Hb[~l&1])
    int gemm_blocks = (N_NODES + 127) / 128;   // 782
    for (int l = 0; l < NLAYERS; ++l) {
        unsigned short* Hout = (l & 1) ? Hb1 : Hb0;
        const unsigned short* Xres = (l & 1) ? Hb0 : Hb1;
        agg_kernel<<<(N_NODES * 16 + 255) / 256, 256, 0, stream>>>(P, row_ptr, col_idx,
                                                                   norm_dst, Q);
        gemm_mfma_kernel<<<gemm_blocks, 256, 0, stream>>>(Q, Wt + (size_t)l * D * D,
                                                          b + (size_t)l * D, Gb, pstats, N_NODES);
        reduce_pstats_kernel<<<16, 256, 0, stream>>>(pstats, pstats2, gemm_blocks);
        bn_finalize_kernel<<<1, 128, 0, stream>>>(pstats2, gamma + (size_t)l * D,
                                                  beta + (size_t)l * D, fin);
        bn_apply_kernel<<<(N_NODES * 16 + 255) / 256, 256, 0, stream>>>(
            Gb, Xres, fin, norm_src, Hout, P, l > 0 ? 1 : 0, l < NLAYERS - 1 ? 1 : 0);
    }

    // ---- pooling + head (final h in Hb1)
    hipMemsetAsync(pooled, 0, (size_t)NGRAPH * D * 4, stream);
    pool_kernel<<<(N_NODES + 1023) / 1024, 256, 0, stream>>>(Hb1, gid, pooled);
    head_kernel<<<4, 256, 0, stream>>>(pooled, Wp, bp, out);
}